// Round 9
// baseline (251.045 us; speedup 1.0000x reference)
//
#include <hip/hip_runtime.h>
#include <math.h>

#define NEG 0.2f

typedef __attribute__((ext_vector_type(8))) short bf16x8;
typedef __attribute__((ext_vector_type(4))) float f32x4;

__device__ __forceinline__ unsigned short f2bf(float f) {
    unsigned u = __float_as_uint(f);
    u += 0x7fffu + ((u >> 16) & 1u);
    return (unsigned short)(u >> 16);
}
__device__ __forceinline__ float blo(unsigned v) { return __uint_as_float(v << 16); }
__device__ __forceinline__ float bhi(unsigned v) { return __uint_as_float(v & 0xffff0000u); }
__device__ __forceinline__ float lrexp(float v) {
    v = v > 0.f ? v : NEG * v;
    return __expf(v);
}

// ---------------------------------------------------------------------------
// K0: W^T precompute -> bf16  Wt[c][k] = W[k][c], c<128 lin, else skip
// ---------------------------------------------------------------------------
__global__ __launch_bounds__(256) void k0_wt(const float* __restrict__ lin_w,
                                             const float* __restrict__ skip_w,
                                             unsigned short* __restrict__ wt)
{
    int idx = blockIdx.x * 256 + threadIdx.x;   // 0..32767
    int k = idx >> 8, c = idx & 255;
    float v = (c < 128) ? lin_w[k * 128 + c] : skip_w[k * 128 + c - 128];
    wt[c * 128 + k] = f2bf(v);
}

// ---------------------------------------------------------------------------
// K1 R9: LDS-free register-streaming MFMA GEMM.
// 512 threads = 8 waves. Wave w: rows bid*64+(w&3)*16, cols (w>>2)*128.
// A-frags (fp32->bf16) and B-frags (bf16) loaded straight global->VGPR;
// no LDS, no barriers, all waves independent.
// ---------------------------------------------------------------------------
__global__ __launch_bounds__(512, 2) void k1_gemm(
    const float* __restrict__ x, const unsigned short* __restrict__ wt,
    const float* __restrict__ att_src, const float* __restrict__ att_dst,
    const float* __restrict__ gat_bias, const float* __restrict__ skip_b,
    unsigned short* __restrict__ xh_bf, float* __restrict__ a_src,
    float* __restrict__ a_dst, float* __restrict__ out, int nrows)
{
    const int t = threadIdx.x;
    const int w = t >> 6, l = t & 63, r = l & 15, half = l >> 4;
    const int cb = w >> 2;                       // 0 = lin half, 1 = skip half
    const int row0 = blockIdx.x * 64 + (w & 3) * 16;
    const bool rowok = (row0 + r) < nrows;
    const float* xrow = x + (size_t)(row0 + r) * 128;

    // A fragments for all 4 k-steps (each: 32 contiguous bytes of one x row)
    bf16x8 aF[4];
#pragma unroll
    for (int ks = 0; ks < 4; ++ks) {
        float4 v0 = make_float4(0.f, 0.f, 0.f, 0.f), v1 = v0;
        if (rowok) {
            const float* gp = xrow + ks * 32 + half * 8;
            v0 = *(const float4*)gp;
            v1 = *(const float4*)(gp + 4);
        }
        bf16x8 a;
        a[0] = f2bf(v0.x); a[1] = f2bf(v0.y); a[2] = f2bf(v0.z); a[3] = f2bf(v0.w);
        a[4] = f2bf(v1.x); a[5] = f2bf(v1.y); a[6] = f2bf(v1.z); a[7] = f2bf(v1.w);
        aF[ks] = a;
    }

    f32x4 acc[8];
#pragma unroll
    for (int cf = 0; cf < 8; ++cf) acc[cf] = (f32x4){0.f, 0.f, 0.f, 0.f};

#pragma unroll
    for (int ks = 0; ks < 4; ++ks) {
#pragma unroll
        for (int cf = 0; cf < 8; ++cf) {
            const int c = cb * 128 + cf * 16 + r;
            bf16x8 bF = *(const bf16x8*)(wt + c * 128 + ks * 32 + half * 8);
            acc[cf] = __builtin_amdgcn_mfma_f32_16x16x32_bf16(aF[ks], bF, acc[cf], 0, 0, 0);
        }
    }

    if (cb == 0) {      // lin half: xh + attention coefficients
#pragma unroll
        for (int cf = 0; cf < 8; ++cf) {
            const int clocal = cf * 16 + r;
            const float as_ = att_src[clocal], ad_ = att_dst[clocal];
#pragma unroll
            for (int q = 0; q < 4; ++q) {
                int row = row0 + half * 4 + q;
                float v = acc[cf][q];
                float s = v * as_, d = v * ad_;
                s += __shfl_xor(s, 1, 16); d += __shfl_xor(d, 1, 16);
                s += __shfl_xor(s, 2, 16); d += __shfl_xor(d, 2, 16);
                s += __shfl_xor(s, 4, 16); d += __shfl_xor(d, 4, 16);
                s += __shfl_xor(s, 8, 16); d += __shfl_xor(d, 8, 16);
                if (row < nrows) {
                    xh_bf[(size_t)row * 128 + clocal] = f2bf(v);
                    if (r == 0) {
                        a_src[(size_t)row * 8 + cf] = s;
                        a_dst[(size_t)row * 8 + cf] = d;
                    }
                }
            }
        }
    } else {            // skip half: out = acc + biases
#pragma unroll
        for (int cf = 0; cf < 8; ++cf) {
            const int clocal = cf * 16 + r;
            const float bb = gat_bias[clocal] + skip_b[clocal];
#pragma unroll
            for (int q = 0; q < 4; ++q) {
                int row = row0 + half * 4 + q;
                if (row < nrows)
                    out[(size_t)row * 128 + clocal] = acc[cf][q] + bb;
            }
        }
    }
}

// ---------------------------------------------------------------------------
// kA: bucket counts only (LDS histogram)
// ---------------------------------------------------------------------------
__global__ __launch_bounds__(256) void kA_hist(const int* __restrict__ ei,
                                               int* __restrict__ bcnt,
                                               int E, int nb)
{
    __shared__ int h[256];
    int t = threadIdx.x;
    h[t] = 0;
    __syncthreads();
    int eb = blockIdx.x * 4096;
#pragma unroll
    for (int u = 0; u < 16; ++u) {
        int e = eb + u * 256 + t;
        if (e < E) atomicAdd(&h[ei[E + e] >> 9], 1);
    }
    __syncthreads();
    if (t < nb && h[t]) atomicAdd(&bcnt[t], h[t]);
}

// ---------------------------------------------------------------------------
// F2: every block LDS-scans bcnt -> bucket bases; bins edges into (dst,src)
// u64 bucket-grouped array.
// ---------------------------------------------------------------------------
__global__ __launch_bounds__(256) void f2(
    const int* __restrict__ ei, const int* __restrict__ bcnt,
    int* __restrict__ fill, unsigned long long* __restrict__ binned,
    int E, int nb)
{
    __shared__ int bs[256];
    __shared__ int bexc[256];
    __shared__ int s1[256];
    __shared__ int s2[256];
    const int t = threadIdx.x;

    int c = (t < nb) ? bcnt[t] : 0;
    bs[t] = c;
    __syncthreads();
    for (int off = 1; off < 256; off <<= 1) {
        int a = (t >= off) ? bs[t - off] : 0;
        __syncthreads();
        bs[t] += a;
        __syncthreads();
    }
    bexc[t] = bs[t] - c;
    __syncthreads();

    s1[t] = 0;
    __syncthreads();
    int eb = blockIdx.x * 4096;
    int srcv[16], dstv[16], rkv[16];
#pragma unroll
    for (int u = 0; u < 16; ++u) {
        int e = eb + u * 256 + t;
        srcv[u] = 0; dstv[u] = -1; rkv[u] = 0;
        if (e < E) {
            srcv[u] = ei[e];
            dstv[u] = ei[E + e];
            rkv[u] = atomicAdd(&s1[dstv[u] >> 9], 1);
        }
    }
    __syncthreads();
    {
        int hc = s1[t];
        s2[t] = bexc[t] + (hc ? atomicAdd(&fill[t], hc) : 0);
    }
    __syncthreads();
#pragma unroll
    for (int u = 0; u < 16; ++u) {
        if (dstv[u] >= 0) {
            int b = dstv[u] >> 9;
            binned[s2[b] + rkv[u]] =
                ((unsigned long long)(unsigned)dstv[u] << 32) | (unsigned)srcv[u];
        }
    }
}

// ---------------------------------------------------------------------------
// F3: one block per bucket (512 nodes). Count bucket nodes in LDS, local
// scan -> rowptr/cntn, then CSR-scatter esrc via LDS cursors.
// ---------------------------------------------------------------------------
__global__ __launch_bounds__(256) void f3(
    const unsigned long long* __restrict__ binned,
    const int* __restrict__ bcnt,
    int* __restrict__ rowptr, int* __restrict__ cntn,
    int* __restrict__ esrc, int N, int nb)
{
    __shared__ int bs[256];
    __shared__ int h[512];
    __shared__ int sc[256];
    const int t = threadIdx.x;
    const int b = blockIdx.x;

    int c = (t < nb) ? bcnt[t] : 0;
    bs[t] = c;
    __syncthreads();
    for (int off = 1; off < 256; off <<= 1) {
        int a = (t >= off) ? bs[t - off] : 0;
        __syncthreads();
        bs[t] += a;
        __syncthreads();
    }
    const int base = bs[b] - bcnt[b];
    const int cnt = bcnt[b];

    h[t] = 0; h[t + 256] = 0;
    __syncthreads();
    for (int e = t; e < cnt; e += 256) {
        int d = (int)(binned[base + e] >> 32);
        atomicAdd(&h[d & 511], 1);
    }
    __syncthreads();
    int i0 = 2 * t, i1 = i0 + 1;
    int c0 = h[i0], c1 = h[i1], pv = c0 + c1;
    sc[t] = pv;
    __syncthreads();
    for (int off = 1; off < 256; off <<= 1) {
        int a = (t >= off) ? sc[t - off] : 0;
        __syncthreads();
        sc[t] += a;
        __syncthreads();
    }
    int ex = sc[t] - pv;
    int n0 = b * 512 + i0;
    if (n0 < N)     { rowptr[n0]     = base + ex;      cntn[n0]     = c0; }
    if (n0 + 1 < N) { rowptr[n0 + 1] = base + ex + c0; cntn[n0 + 1] = c1; }
    h[i0] = base + ex;
    h[i1] = base + ex + c0;
    __syncthreads();
    for (int e = t; e < cnt; e += 256) {
        unsigned long long p = binned[base + e];
        int d = (int)(p >> 32), s = (int)(p & 0xffffffffu);
        int slot = atomicAdd(&h[d & 511], 1);
        esrc[slot] = s;
    }
}

// ---------------------------------------------------------------------------
// K3: fused denom + aggregation + skip + ELU (unchanged — at gather roofline)
// ---------------------------------------------------------------------------
__global__ __launch_bounds__(256) void k3_agg(
    const int* __restrict__ rowptr, const int* __restrict__ cntn,
    const int* __restrict__ esrc,
    const float* __restrict__ a_src, const float* __restrict__ a_dst,
    const unsigned int* __restrict__ xh32, float* __restrict__ out, int n)
{
    int i = blockIdx.x * 4 + (threadIdx.x >> 6);
    if (i >= n) return;
    const int lane = threadIdx.x & 63;
    const int h = lane >> 3, u = lane & 7;

    float adi = a_dst[(unsigned)i * 8 + h];
    float p0 = lrexp(a_src[(unsigned)i * 8 + h] + adi);
    unsigned uu = xh32[(unsigned)i * 64 + lane];
    float accx = p0 * blo(uu), accy = p0 * bhi(uu), den = p0;

    const int kbeg = rowptr[i], kend = kbeg + cntn[i];
    for (int k = kbeg; k < kend; k += 8) {
        int ke = k + u;
        int jm = esrc[ke];
        float pmv = lrexp(a_src[(unsigned)jm * 8 + h] + adi);
        float pm = (ke < kend) ? pmv : 0.f;

        int j0 = esrc[k],     j1 = esrc[k + 1], j2 = esrc[k + 2], j3 = esrc[k + 3];
        int j4 = esrc[k + 4], j5 = esrc[k + 5], j6 = esrc[k + 6], j7 = esrc[k + 7];
        unsigned g0 = xh32[(unsigned)j0 * 64 + lane];
        unsigned g1 = xh32[(unsigned)j1 * 64 + lane];
        unsigned g2 = xh32[(unsigned)j2 * 64 + lane];
        unsigned g3 = xh32[(unsigned)j3 * 64 + lane];
        unsigned g4 = xh32[(unsigned)j4 * 64 + lane];
        unsigned g5 = xh32[(unsigned)j5 * 64 + lane];
        unsigned g6 = xh32[(unsigned)j6 * 64 + lane];
        unsigned g7 = xh32[(unsigned)j7 * 64 + lane];

        int sb = lane & 56;
        float p;
        p = __shfl(pm, sb | 0, 64); accx += p * blo(g0); accy += p * bhi(g0); den += p;
        p = __shfl(pm, sb | 1, 64); accx += p * blo(g1); accy += p * bhi(g1); den += p;
        p = __shfl(pm, sb | 2, 64); accx += p * blo(g2); accy += p * bhi(g2); den += p;
        p = __shfl(pm, sb | 3, 64); accx += p * blo(g3); accy += p * bhi(g3); den += p;
        p = __shfl(pm, sb | 4, 64); accx += p * blo(g4); accy += p * bhi(g4); den += p;
        p = __shfl(pm, sb | 5, 64); accx += p * blo(g5); accy += p * bhi(g5); den += p;
        p = __shfl(pm, sb | 6, 64); accx += p * blo(g6); accy += p * bhi(g6); den += p;
        p = __shfl(pm, sb | 7, 64); accx += p * blo(g7); accy += p * bhi(g7); den += p;
    }

    float inv = 1.f / (den + 1e-16f);
    unsigned o = (unsigned)i * 128 + lane * 2;
    float o0 = out[o]     + accx * inv;
    float o1 = out[o + 1] + accy * inv;
    o0 = o0 > 0.f ? o0 : __expf(o0) - 1.f;
    o1 = o1 > 0.f ? o1 : __expf(o1) - 1.f;
    out[o]     = o0;
    out[o + 1] = o1;
}

extern "C" void kernel_launch(void* const* d_in, const int* in_sizes, int n_in,
                              void* d_out, int out_size, void* d_ws, size_t ws_size,
                              hipStream_t stream)
{
    const float* x        = (const float*)d_in[0];
    const int*   ei       = (const int*)d_in[1];
    const float* lin_w    = (const float*)d_in[2];
    const float* att_src  = (const float*)d_in[3];
    const float* att_dst  = (const float*)d_in[4];
    const float* gat_bias = (const float*)d_in[5];
    const float* skip_w   = (const float*)d_in[6];
    const float* skip_b   = (const float*)d_in[7];
    float* out = (float*)d_out;

    const int N = in_sizes[0] / 128;
    const int E = in_sizes[1] / 2;
    const int nb  = (N + 511) >> 9;            // buckets of 512 nodes (<=256)
    const int nba = (E + 4095) / 4096;         // edge blocks

    float* ws   = (float*)d_ws;
    float* asrc = ws;                                   // N*8 f
    float* adst = asrc + (size_t)N * 8;                 // N*8 f
    unsigned short* wt = (unsigned short*)(adst + (size_t)N * 8);     // 32768 bf16
    unsigned short* xh_bf = wt + 32768;                 // N*128 bf16
    int* cntn   = (int*)(xh_bf + (size_t)N * 128);      // N
    int* rowptr = cntn + N;                             // N
    int* esrc   = rowptr + N;                           // E+8 (padded)
    int* bcnt   = esrc + E + 8;                         // 256
    int* fill   = bcnt + 256;                           // 256
    unsigned long long* binned =
        (unsigned long long*)(((size_t)(fill + 256) + 15) & ~(size_t)15);

    hipMemsetAsync(esrc + E, 0, (8 + 512) * sizeof(int), stream);

    k0_wt<<<128, 256, 0, stream>>>(lin_w, skip_w, wt);

    k1_gemm<<<(N + 63) / 64, 512, 0, stream>>>(
        x, wt, att_src, att_dst, gat_bias, skip_b, xh_bf, asrc, adst, out, N);

    kA_hist<<<nba, 256, 0, stream>>>(ei, bcnt, E, nb);

    f2<<<nba, 256, 0, stream>>>(ei, bcnt, fill, binned, E, nb);

    f3<<<nb, 256, 0, stream>>>(binned, bcnt, rowptr, cntn, esrc, N, nb);

    k3_agg<<<(N + 3) / 4, 256, 0, stream>>>(rowptr, cntn, esrc, asrc, adst,
                                            (const unsigned int*)xh_bf, out, N);
}

// Round 10
// 244.653 us; speedup vs baseline: 1.0261x; 1.0261x over previous
//
#include <hip/hip_runtime.h>
#include <math.h>

#define NEG 0.2f

typedef __attribute__((ext_vector_type(8))) short bf16x8;
typedef __attribute__((ext_vector_type(4))) float f32x4;

__device__ __forceinline__ unsigned short f2bf(float f) {
    unsigned u = __float_as_uint(f);
    u += 0x7fffu + ((u >> 16) & 1u);
    return (unsigned short)(u >> 16);
}
__device__ __forceinline__ float blo(unsigned v) { return __uint_as_float(v << 16); }
__device__ __forceinline__ float bhi(unsigned v) { return __uint_as_float(v & 0xffff0000u); }
__device__ __forceinline__ float lrexp(float v) {
    v = v > 0.f ? v : NEG * v;
    return __expf(v);
}

// ---------------------------------------------------------------------------
// K0: build wt2 [272][128] bf16, column-major-transposed weights:
//   c in [0,128)  : lin_w column c
//   c in [128,256): skip_w column c-128
//   c in [256,264): w_as head c-256  (= lin_w @ att_src, per head)
//   c in [264,272): w_ad head c-264  (= lin_w @ att_dst, per head)
// ---------------------------------------------------------------------------
__global__ __launch_bounds__(256) void k0_wt(
    const float* __restrict__ lin_w, const float* __restrict__ skip_w,
    const float* __restrict__ att_src, const float* __restrict__ att_dst,
    unsigned short* __restrict__ wt)
{
    int idx = blockIdx.x * 256 + threadIdx.x;   // 0..34815
    int c = idx >> 7, k = idx & 127;
    float v;
    if (c < 128) {
        v = lin_w[k * 128 + c];
    } else if (c < 256) {
        v = skip_w[k * 128 + (c - 128)];
    } else {
        int hh = c & 7;
        const float* att = (c & 8) ? att_dst : att_src;
        const float* wrow = lin_w + k * 128 + hh * 16;
        float s = 0.f;
#pragma unroll
        for (int j = 0; j < 16; ++j) s += wrow[j] * att[hh * 16 + j];
        v = s;
    }
    wt[c * 128 + k] = f2bf(v);
}

// ---------------------------------------------------------------------------
// K1 R10: LDS-free register-streaming MFMA GEMM, attention coefficients as
// an extra MFMA fragment (no cross-lane reduce).
// 512 threads = 8 waves. Wave w: rows bid*64+(w&3)*16, cols (w>>2)*128.
// cb==0 waves also compute cols 256..271 = [a_src heads | a_dst heads].
// ---------------------------------------------------------------------------
__global__ __launch_bounds__(512) void k1_gemm(
    const float* __restrict__ x, const unsigned short* __restrict__ wt,
    const float* __restrict__ gat_bias, const float* __restrict__ skip_b,
    unsigned short* __restrict__ xh_bf, float* __restrict__ a_src,
    float* __restrict__ a_dst, float* __restrict__ out, int nrows)
{
    const int t = threadIdx.x;
    const int w = t >> 6, l = t & 63, r = l & 15, half = l >> 4;
    const int cb = w >> 2;                       // 0 = lin half, 1 = skip half
    const int row0 = blockIdx.x * 64 + (w & 3) * 16;
    const bool rowok = (row0 + r) < nrows;
    const float* xrow = x + (size_t)(row0 + r) * 128;

    // A fragments for all 4 k-steps (each: 32 contiguous bytes of one x row)
    bf16x8 aF[4];
#pragma unroll
    for (int ks = 0; ks < 4; ++ks) {
        float4 v0 = make_float4(0.f, 0.f, 0.f, 0.f), v1 = v0;
        if (rowok) {
            const float* gp = xrow + ks * 32 + half * 8;
            v0 = *(const float4*)gp;
            v1 = *(const float4*)(gp + 4);
        }
        bf16x8 a;
        a[0] = f2bf(v0.x); a[1] = f2bf(v0.y); a[2] = f2bf(v0.z); a[3] = f2bf(v0.w);
        a[4] = f2bf(v1.x); a[5] = f2bf(v1.y); a[6] = f2bf(v1.z); a[7] = f2bf(v1.w);
        aF[ks] = a;
    }

    f32x4 acc[8];
#pragma unroll
    for (int cf = 0; cf < 8; ++cf) acc[cf] = (f32x4){0.f, 0.f, 0.f, 0.f};
    f32x4 accA = (f32x4){0.f, 0.f, 0.f, 0.f};

#pragma unroll
    for (int ks = 0; ks < 4; ++ks) {
#pragma unroll
        for (int cf = 0; cf < 8; ++cf) {
            const int c = cb * 128 + cf * 16 + r;
            bf16x8 bF = *(const bf16x8*)(wt + c * 128 + ks * 32 + half * 8);
            acc[cf] = __builtin_amdgcn_mfma_f32_16x16x32_bf16(aF[ks], bF, acc[cf], 0, 0, 0);
        }
        if (cb == 0) {   // attention fragment: cols 256..271
            bf16x8 bA = *(const bf16x8*)(wt + (256 + r) * 128 + ks * 32 + half * 8);
            accA = __builtin_amdgcn_mfma_f32_16x16x32_bf16(aF[ks], bA, accA, 0, 0, 0);
        }
    }

    if (cb == 0) {      // lin half: xh stores + direct a_src/a_dst stores
#pragma unroll
        for (int cf = 0; cf < 8; ++cf) {
            const int clocal = cf * 16 + r;
#pragma unroll
            for (int q = 0; q < 4; ++q) {
                int row = row0 + half * 4 + q;
                if (row < nrows)
                    xh_bf[(size_t)row * 128 + clocal] = f2bf(acc[cf][q]);
            }
        }
#pragma unroll
        for (int q = 0; q < 4; ++q) {
            int row = row0 + half * 4 + q;
            if (row < nrows) {
                float v = accA[q];
                if (r < 8) a_src[(size_t)row * 8 + r] = v;
                else       a_dst[(size_t)row * 8 + (r - 8)] = v;
            }
        }
    } else {            // skip half: out = acc + biases
#pragma unroll
        for (int cf = 0; cf < 8; ++cf) {
            const int clocal = cf * 16 + r;
            const float bb = gat_bias[clocal] + skip_b[clocal];
#pragma unroll
            for (int q = 0; q < 4; ++q) {
                int row = row0 + half * 4 + q;
                if (row < nrows)
                    out[(size_t)row * 128 + clocal] = acc[cf][q] + bb;
            }
        }
    }
}

// ---------------------------------------------------------------------------
// kA: bucket counts only (LDS histogram)
// ---------------------------------------------------------------------------
__global__ __launch_bounds__(256) void kA_hist(const int* __restrict__ ei,
                                               int* __restrict__ bcnt,
                                               int E, int nb)
{
    __shared__ int h[256];
    int t = threadIdx.x;
    h[t] = 0;
    __syncthreads();
    int eb = blockIdx.x * 4096;
#pragma unroll
    for (int u = 0; u < 16; ++u) {
        int e = eb + u * 256 + t;
        if (e < E) atomicAdd(&h[ei[E + e] >> 9], 1);
    }
    __syncthreads();
    if (t < nb && h[t]) atomicAdd(&bcnt[t], h[t]);
}

// ---------------------------------------------------------------------------
// F2: every block LDS-scans bcnt -> bucket bases; bins edges into (dst,src)
// u64 bucket-grouped array.
// ---------------------------------------------------------------------------
__global__ __launch_bounds__(256) void f2(
    const int* __restrict__ ei, const int* __restrict__ bcnt,
    int* __restrict__ fill, unsigned long long* __restrict__ binned,
    int E, int nb)
{
    __shared__ int bs[256];
    __shared__ int bexc[256];
    __shared__ int s1[256];
    __shared__ int s2[256];
    const int t = threadIdx.x;

    int c = (t < nb) ? bcnt[t] : 0;
    bs[t] = c;
    __syncthreads();
    for (int off = 1; off < 256; off <<= 1) {
        int a = (t >= off) ? bs[t - off] : 0;
        __syncthreads();
        bs[t] += a;
        __syncthreads();
    }
    bexc[t] = bs[t] - c;
    __syncthreads();

    s1[t] = 0;
    __syncthreads();
    int eb = blockIdx.x * 4096;
    int srcv[16], dstv[16], rkv[16];
#pragma unroll
    for (int u = 0; u < 16; ++u) {
        int e = eb + u * 256 + t;
        srcv[u] = 0; dstv[u] = -1; rkv[u] = 0;
        if (e < E) {
            srcv[u] = ei[e];
            dstv[u] = ei[E + e];
            rkv[u] = atomicAdd(&s1[dstv[u] >> 9], 1);
        }
    }
    __syncthreads();
    {
        int hc = s1[t];
        s2[t] = bexc[t] + (hc ? atomicAdd(&fill[t], hc) : 0);
    }
    __syncthreads();
#pragma unroll
    for (int u = 0; u < 16; ++u) {
        if (dstv[u] >= 0) {
            int b = dstv[u] >> 9;
            binned[s2[b] + rkv[u]] =
                ((unsigned long long)(unsigned)dstv[u] << 32) | (unsigned)srcv[u];
        }
    }
}

// ---------------------------------------------------------------------------
// F3: one block per bucket (512 nodes). Count bucket nodes in LDS, local
// scan -> rowptr/cntn, then CSR-scatter esrc via LDS cursors.
// ---------------------------------------------------------------------------
__global__ __launch_bounds__(256) void f3(
    const unsigned long long* __restrict__ binned,
    const int* __restrict__ bcnt,
    int* __restrict__ rowptr, int* __restrict__ cntn,
    int* __restrict__ esrc, int N, int nb)
{
    __shared__ int bs[256];
    __shared__ int h[512];
    __shared__ int sc[256];
    const int t = threadIdx.x;
    const int b = blockIdx.x;

    int c = (t < nb) ? bcnt[t] : 0;
    bs[t] = c;
    __syncthreads();
    for (int off = 1; off < 256; off <<= 1) {
        int a = (t >= off) ? bs[t - off] : 0;
        __syncthreads();
        bs[t] += a;
        __syncthreads();
    }
    const int base = bs[b] - bcnt[b];
    const int cnt = bcnt[b];

    h[t] = 0; h[t + 256] = 0;
    __syncthreads();
    for (int e = t; e < cnt; e += 256) {
        int d = (int)(binned[base + e] >> 32);
        atomicAdd(&h[d & 511], 1);
    }
    __syncthreads();
    int i0 = 2 * t, i1 = i0 + 1;
    int c0 = h[i0], c1 = h[i1], pv = c0 + c1;
    sc[t] = pv;
    __syncthreads();
    for (int off = 1; off < 256; off <<= 1) {
        int a = (t >= off) ? sc[t - off] : 0;
        __syncthreads();
        sc[t] += a;
        __syncthreads();
    }
    int ex = sc[t] - pv;
    int n0 = b * 512 + i0;
    if (n0 < N)     { rowptr[n0]     = base + ex;      cntn[n0]     = c0; }
    if (n0 + 1 < N) { rowptr[n0 + 1] = base + ex + c0; cntn[n0 + 1] = c1; }
    h[i0] = base + ex;
    h[i1] = base + ex + c0;
    __syncthreads();
    for (int e = t; e < cnt; e += 256) {
        unsigned long long p = binned[base + e];
        int d = (int)(p >> 32), s = (int)(p & 0xffffffffu);
        int slot = atomicAdd(&h[d & 511], 1);
        esrc[slot] = s;
    }
}

// ---------------------------------------------------------------------------
// K3: fused denom + aggregation + skip + ELU (unchanged — at gather roofline)
// ---------------------------------------------------------------------------
__global__ __launch_bounds__(256) void k3_agg(
    const int* __restrict__ rowptr, const int* __restrict__ cntn,
    const int* __restrict__ esrc,
    const float* __restrict__ a_src, const float* __restrict__ a_dst,
    const unsigned int* __restrict__ xh32, float* __restrict__ out, int n)
{
    int i = blockIdx.x * 4 + (threadIdx.x >> 6);
    if (i >= n) return;
    const int lane = threadIdx.x & 63;
    const int h = lane >> 3, u = lane & 7;

    float adi = a_dst[(unsigned)i * 8 + h];
    float p0 = lrexp(a_src[(unsigned)i * 8 + h] + adi);
    unsigned uu = xh32[(unsigned)i * 64 + lane];
    float accx = p0 * blo(uu), accy = p0 * bhi(uu), den = p0;

    const int kbeg = rowptr[i], kend = kbeg + cntn[i];
    for (int k = kbeg; k < kend; k += 8) {
        int ke = k + u;
        int jm = esrc[ke];
        float pmv = lrexp(a_src[(unsigned)jm * 8 + h] + adi);
        float pm = (ke < kend) ? pmv : 0.f;

        int j0 = esrc[k],     j1 = esrc[k + 1], j2 = esrc[k + 2], j3 = esrc[k + 3];
        int j4 = esrc[k + 4], j5 = esrc[k + 5], j6 = esrc[k + 6], j7 = esrc[k + 7];
        unsigned g0 = xh32[(unsigned)j0 * 64 + lane];
        unsigned g1 = xh32[(unsigned)j1 * 64 + lane];
        unsigned g2 = xh32[(unsigned)j2 * 64 + lane];
        unsigned g3 = xh32[(unsigned)j3 * 64 + lane];
        unsigned g4 = xh32[(unsigned)j4 * 64 + lane];
        unsigned g5 = xh32[(unsigned)j5 * 64 + lane];
        unsigned g6 = xh32[(unsigned)j6 * 64 + lane];
        unsigned g7 = xh32[(unsigned)j7 * 64 + lane];

        int sb = lane & 56;
        float p;
        p = __shfl(pm, sb | 0, 64); accx += p * blo(g0); accy += p * bhi(g0); den += p;
        p = __shfl(pm, sb | 1, 64); accx += p * blo(g1); accy += p * bhi(g1); den += p;
        p = __shfl(pm, sb | 2, 64); accx += p * blo(g2); accy += p * bhi(g2); den += p;
        p = __shfl(pm, sb | 3, 64); accx += p * blo(g3); accy += p * bhi(g3); den += p;
        p = __shfl(pm, sb | 4, 64); accx += p * blo(g4); accy += p * bhi(g4); den += p;
        p = __shfl(pm, sb | 5, 64); accx += p * blo(g5); accy += p * bhi(g5); den += p;
        p = __shfl(pm, sb | 6, 64); accx += p * blo(g6); accy += p * bhi(g6); den += p;
        p = __shfl(pm, sb | 7, 64); accx += p * blo(g7); accy += p * bhi(g7); den += p;
    }

    float inv = 1.f / (den + 1e-16f);
    unsigned o = (unsigned)i * 128 + lane * 2;
    float o0 = out[o]     + accx * inv;
    float o1 = out[o + 1] + accy * inv;
    o0 = o0 > 0.f ? o0 : __expf(o0) - 1.f;
    o1 = o1 > 0.f ? o1 : __expf(o1) - 1.f;
    out[o]     = o0;
    out[o + 1] = o1;
}

extern "C" void kernel_launch(void* const* d_in, const int* in_sizes, int n_in,
                              void* d_out, int out_size, void* d_ws, size_t ws_size,
                              hipStream_t stream)
{
    const float* x        = (const float*)d_in[0];
    const int*   ei       = (const int*)d_in[1];
    const float* lin_w    = (const float*)d_in[2];
    const float* att_src  = (const float*)d_in[3];
    const float* att_dst  = (const float*)d_in[4];
    const float* gat_bias = (const float*)d_in[5];
    const float* skip_w   = (const float*)d_in[6];
    const float* skip_b   = (const float*)d_in[7];
    float* out = (float*)d_out;

    const int N = in_sizes[0] / 128;
    const int E = in_sizes[1] / 2;
    const int nb  = (N + 511) >> 9;            // buckets of 512 nodes (<=256)
    const int nba = (E + 4095) / 4096;         // edge blocks

    float* ws   = (float*)d_ws;
    float* asrc = ws;                                   // N*8 f
    float* adst = asrc + (size_t)N * 8;                 // N*8 f
    unsigned short* wt = (unsigned short*)(adst + (size_t)N * 8);     // 272*128 bf16
    unsigned short* xh_bf = wt + 272 * 128;             // N*128 bf16
    int* cntn   = (int*)(xh_bf + (size_t)N * 128);      // N
    int* rowptr = cntn + N;                             // N
    int* esrc   = rowptr + N;                           // E+8 (padded)
    int* bcnt   = esrc + E + 8;                         // 256
    int* fill   = bcnt + 256;                           // 256
    unsigned long long* binned =
        (unsigned long long*)(((size_t)(fill + 256) + 15) & ~(size_t)15);

    hipMemsetAsync(esrc + E, 0, (8 + 512) * sizeof(int), stream);

    k0_wt<<<136, 256, 0, stream>>>(lin_w, skip_w, att_src, att_dst, wt);

    k1_gemm<<<(N + 63) / 64, 512, 0, stream>>>(
        x, wt, gat_bias, skip_b, xh_bf, asrc, adst, out, N);

    kA_hist<<<nba, 256, 0, stream>>>(ei, bcnt, E, nb);

    f2<<<nba, 256, 0, stream>>>(ei, bcnt, fill, binned, E, nb);

    f3<<<nb, 256, 0, stream>>>(binned, bcnt, rowptr, cntn, esrc, N, nb);

    k3_agg<<<(N + 3) / 4, 256, 0, stream>>>(rowptr, cntn, esrc, asrc, adst,
                                            (const unsigned int*)xh_bf, out, N);
}

// Round 11
// 209.801 us; speedup vs baseline: 1.1966x; 1.1661x over previous
//
#include <hip/hip_runtime.h>
#include <math.h>

#define NEG 0.2f
#define BCAP 10240            // per-bucket slab capacity (mean 8163, +23 sigma)

typedef __attribute__((ext_vector_type(8))) short bf16x8;
typedef __attribute__((ext_vector_type(4))) float f32x4;

__device__ __forceinline__ unsigned short f2bf(float f) {
    unsigned u = __float_as_uint(f);
    u += 0x7fffu + ((u >> 16) & 1u);
    return (unsigned short)(u >> 16);
}
__device__ __forceinline__ float blo(unsigned v) { return __uint_as_float(v << 16); }
__device__ __forceinline__ float bhi(unsigned v) { return __uint_as_float(v & 0xffff0000u); }
__device__ __forceinline__ float lrexp(float v) {
    v = v > 0.f ? v : NEG * v;
    return __expf(v);
}

// ---------------------------------------------------------------------------
// K0: build wt [272][128] bf16 transposed weights (lin | skip | w_as | w_ad)
// ---------------------------------------------------------------------------
__global__ __launch_bounds__(256) void k0_wt(
    const float* __restrict__ lin_w, const float* __restrict__ skip_w,
    const float* __restrict__ att_src, const float* __restrict__ att_dst,
    unsigned short* __restrict__ wt)
{
    int idx = blockIdx.x * 256 + threadIdx.x;   // 0..34815
    int c = idx >> 7, k = idx & 127;
    float v;
    if (c < 128) {
        v = lin_w[k * 128 + c];
    } else if (c < 256) {
        v = skip_w[k * 128 + (c - 128)];
    } else {
        int hh = c & 7;
        const float* att = (c & 8) ? att_dst : att_src;
        const float* wrow = lin_w + k * 128 + hh * 16;
        float s = 0.f;
#pragma unroll
        for (int j = 0; j < 16; ++j) s += wrow[j] * att[hh * 16 + j];
        v = s;
    }
    wt[c * 128 + k] = f2bf(v);
}

// ---------------------------------------------------------------------------
// K1F: [blocks 0..nbin)   = edge binning into fixed-CAP bucket slabs (u32)
//      [blocks nbin..)    = LDS-free register-streaming MFMA GEMM (R10 form)
// ---------------------------------------------------------------------------
__global__ __launch_bounds__(512) void k1f(
    const float* __restrict__ x, const unsigned short* __restrict__ wt,
    const float* __restrict__ gat_bias, const float* __restrict__ skip_b,
    const int* __restrict__ ei,
    unsigned short* __restrict__ xh_bf, float* __restrict__ a_src,
    float* __restrict__ a_dst, float* __restrict__ out,
    int* __restrict__ fill, unsigned* __restrict__ binned,
    int nrows, int E, int nbin)
{
    __shared__ int s1[256];
    __shared__ int s2[256];
    const int t = threadIdx.x;
    const int bid = blockIdx.x;

    if (bid < nbin) {                 // ---- binning role ----
        if (t < 256) s1[t] = 0;
        __syncthreads();
        int eb = bid * 8192;
        int srcv[16], dstv[16], rkv[16];
#pragma unroll
        for (int u = 0; u < 16; ++u) {
            int e = eb + u * 512 + t;
            srcv[u] = 0; dstv[u] = -1; rkv[u] = 0;
            if (e < E) {
                srcv[u] = ei[e];
                dstv[u] = ei[E + e];
                rkv[u] = atomicAdd(&s1[dstv[u] >> 9], 1);
            }
        }
        __syncthreads();
        if (t < 256) {
            int hc = s1[t];
            s2[t] = t * BCAP + (hc ? atomicAdd(&fill[t], hc) : 0);
        }
        __syncthreads();
#pragma unroll
        for (int u = 0; u < 16; ++u) {
            if (dstv[u] >= 0) {
                int b = dstv[u] >> 9;
                binned[s2[b] + rkv[u]] =
                    ((unsigned)(dstv[u] & 511) << 17) | (unsigned)srcv[u];
            }
        }
        return;
    }

    // ---- GEMM role (R10 structure, unchanged algebra) ----
    const int w = t >> 6, l = t & 63, r = l & 15, half = l >> 4;
    const int cb = w >> 2;
    const int row0 = (bid - nbin) * 64 + (w & 3) * 16;
    const bool rowok = (row0 + r) < nrows;
    const float* xrow = x + (size_t)(row0 + r) * 128;

    bf16x8 aF[4];
#pragma unroll
    for (int ks = 0; ks < 4; ++ks) {
        float4 v0 = make_float4(0.f, 0.f, 0.f, 0.f), v1 = v0;
        if (rowok) {
            const float* gp = xrow + ks * 32 + half * 8;
            v0 = *(const float4*)gp;
            v1 = *(const float4*)(gp + 4);
        }
        bf16x8 a;
        a[0] = f2bf(v0.x); a[1] = f2bf(v0.y); a[2] = f2bf(v0.z); a[3] = f2bf(v0.w);
        a[4] = f2bf(v1.x); a[5] = f2bf(v1.y); a[6] = f2bf(v1.z); a[7] = f2bf(v1.w);
        aF[ks] = a;
    }

    f32x4 acc[8];
#pragma unroll
    for (int cf = 0; cf < 8; ++cf) acc[cf] = (f32x4){0.f, 0.f, 0.f, 0.f};
    f32x4 accA = (f32x4){0.f, 0.f, 0.f, 0.f};

#pragma unroll
    for (int ks = 0; ks < 4; ++ks) {
#pragma unroll
        for (int cf = 0; cf < 8; ++cf) {
            const int c = cb * 128 + cf * 16 + r;
            bf16x8 bF = *(const bf16x8*)(wt + c * 128 + ks * 32 + half * 8);
            acc[cf] = __builtin_amdgcn_mfma_f32_16x16x32_bf16(aF[ks], bF, acc[cf], 0, 0, 0);
        }
        if (cb == 0) {
            bf16x8 bA = *(const bf16x8*)(wt + (256 + r) * 128 + ks * 32 + half * 8);
            accA = __builtin_amdgcn_mfma_f32_16x16x32_bf16(aF[ks], bA, accA, 0, 0, 0);
        }
    }

    if (cb == 0) {
#pragma unroll
        for (int cf = 0; cf < 8; ++cf) {
            const int clocal = cf * 16 + r;
#pragma unroll
            for (int q = 0; q < 4; ++q) {
                int row = row0 + half * 4 + q;
                if (row < nrows)
                    xh_bf[(size_t)row * 128 + clocal] = f2bf(acc[cf][q]);
            }
        }
#pragma unroll
        for (int q = 0; q < 4; ++q) {
            int row = row0 + half * 4 + q;
            if (row < nrows) {
                float v = accA[q];
                if (r < 8) a_src[(size_t)row * 8 + r] = v;
                else       a_dst[(size_t)row * 8 + (r - 8)] = v;
            }
        }
    } else {
#pragma unroll
        for (int cf = 0; cf < 8; ++cf) {
            const int clocal = cf * 16 + r;
            const float bb = gat_bias[clocal] + skip_b[clocal];
#pragma unroll
            for (int q = 0; q < 4; ++q) {
                int row = row0 + half * 4 + q;
                if (row < nrows)
                    out[(size_t)row * 128 + clocal] = acc[cf][q] + bb;
            }
        }
    }
}

// ---------------------------------------------------------------------------
// F3: one block per bucket (512 nodes). Single pass: slab -> LDS, node hist,
// local scan -> rowptr/cntn, scatter esrc from LDS.
// ---------------------------------------------------------------------------
__global__ __launch_bounds__(256) void f3(
    const unsigned* __restrict__ binned, const int* __restrict__ fill,
    int* __restrict__ rowptr, int* __restrict__ cntn,
    int* __restrict__ esrc, int N, int nb)
{
    __shared__ unsigned le[BCAP];    // 40 KB
    __shared__ int bs[256];
    __shared__ int h[512];
    __shared__ int sc[256];
    const int t = threadIdx.x;
    const int b = blockIdx.x;

    int c = (t < nb) ? fill[t] : 0;
    bs[t] = c;
    __syncthreads();
    for (int off = 1; off < 256; off <<= 1) {
        int a = (t >= off) ? bs[t - off] : 0;
        __syncthreads();
        bs[t] += a;
        __syncthreads();
    }
    const int cnt = fill[b];
    const int baseE = bs[b] - cnt;   // exclusive scan value for bucket b

    h[t] = 0; h[t + 256] = 0;
    __syncthreads();
    for (int e = t; e < cnt; e += 256) {
        unsigned p = binned[b * BCAP + e];
        le[e] = p;
        atomicAdd(&h[p >> 17], 1);
    }
    __syncthreads();
    int i0 = 2 * t, i1 = i0 + 1;
    int c0 = h[i0], c1 = h[i1], pv = c0 + c1;
    sc[t] = pv;
    __syncthreads();
    for (int off = 1; off < 256; off <<= 1) {
        int a = (t >= off) ? sc[t - off] : 0;
        __syncthreads();
        sc[t] += a;
        __syncthreads();
    }
    int ex = sc[t] - pv;
    int n0 = b * 512 + i0;
    if (n0 < N)     { rowptr[n0]     = baseE + ex;      cntn[n0]     = c0; }
    if (n0 + 1 < N) { rowptr[n0 + 1] = baseE + ex + c0; cntn[n0 + 1] = c1; }
    h[i0] = baseE + ex;
    h[i1] = baseE + ex + c0;
    __syncthreads();
    for (int e = t; e < cnt; e += 256) {
        unsigned p = le[e];
        int slot = atomicAdd(&h[p >> 17], 1);
        esrc[slot] = (int)(p & 0x1FFFFu);
    }
}

// ---------------------------------------------------------------------------
// K3: fused denom + aggregation + skip + ELU (unchanged — at gather roofline)
// ---------------------------------------------------------------------------
__global__ __launch_bounds__(256) void k3_agg(
    const int* __restrict__ rowptr, const int* __restrict__ cntn,
    const int* __restrict__ esrc,
    const float* __restrict__ a_src, const float* __restrict__ a_dst,
    const unsigned int* __restrict__ xh32, float* __restrict__ out, int n)
{
    int i = blockIdx.x * 4 + (threadIdx.x >> 6);
    if (i >= n) return;
    const int lane = threadIdx.x & 63;
    const int h = lane >> 3, u = lane & 7;

    float adi = a_dst[(unsigned)i * 8 + h];
    float p0 = lrexp(a_src[(unsigned)i * 8 + h] + adi);
    unsigned uu = xh32[(unsigned)i * 64 + lane];
    float accx = p0 * blo(uu), accy = p0 * bhi(uu), den = p0;

    const int kbeg = rowptr[i], kend = kbeg + cntn[i];
    for (int k = kbeg; k < kend; k += 8) {
        int ke = k + u;
        int jm = esrc[ke];
        float pmv = lrexp(a_src[(unsigned)jm * 8 + h] + adi);
        float pm = (ke < kend) ? pmv : 0.f;

        int j0 = esrc[k],     j1 = esrc[k + 1], j2 = esrc[k + 2], j3 = esrc[k + 3];
        int j4 = esrc[k + 4], j5 = esrc[k + 5], j6 = esrc[k + 6], j7 = esrc[k + 7];
        unsigned g0 = xh32[(unsigned)j0 * 64 + lane];
        unsigned g1 = xh32[(unsigned)j1 * 64 + lane];
        unsigned g2 = xh32[(unsigned)j2 * 64 + lane];
        unsigned g3 = xh32[(unsigned)j3 * 64 + lane];
        unsigned g4 = xh32[(unsigned)j4 * 64 + lane];
        unsigned g5 = xh32[(unsigned)j5 * 64 + lane];
        unsigned g6 = xh32[(unsigned)j6 * 64 + lane];
        unsigned g7 = xh32[(unsigned)j7 * 64 + lane];

        int sb = lane & 56;
        float p;
        p = __shfl(pm, sb | 0, 64); accx += p * blo(g0); accy += p * bhi(g0); den += p;
        p = __shfl(pm, sb | 1, 64); accx += p * blo(g1); accy += p * bhi(g1); den += p;
        p = __shfl(pm, sb | 2, 64); accx += p * blo(g2); accy += p * bhi(g2); den += p;
        p = __shfl(pm, sb | 3, 64); accx += p * blo(g3); accy += p * bhi(g3); den += p;
        p = __shfl(pm, sb | 4, 64); accx += p * blo(g4); accy += p * bhi(g4); den += p;
        p = __shfl(pm, sb | 5, 64); accx += p * blo(g5); accy += p * bhi(g5); den += p;
        p = __shfl(pm, sb | 6, 64); accx += p * blo(g6); accy += p * bhi(g6); den += p;
        p = __shfl(pm, sb | 7, 64); accx += p * blo(g7); accy += p * bhi(g7); den += p;
    }

    float inv = 1.f / (den + 1e-16f);
    unsigned o = (unsigned)i * 128 + lane * 2;
    float o0 = out[o]     + accx * inv;
    float o1 = out[o + 1] + accy * inv;
    o0 = o0 > 0.f ? o0 : __expf(o0) - 1.f;
    o1 = o1 > 0.f ? o1 : __expf(o1) - 1.f;
    out[o]     = o0;
    out[o + 1] = o1;
}

extern "C" void kernel_launch(void* const* d_in, const int* in_sizes, int n_in,
                              void* d_out, int out_size, void* d_ws, size_t ws_size,
                              hipStream_t stream)
{
    const float* x        = (const float*)d_in[0];
    const int*   ei       = (const int*)d_in[1];
    const float* lin_w    = (const float*)d_in[2];
    const float* att_src  = (const float*)d_in[3];
    const float* att_dst  = (const float*)d_in[4];
    const float* gat_bias = (const float*)d_in[5];
    const float* skip_w   = (const float*)d_in[6];
    const float* skip_b   = (const float*)d_in[7];
    float* out = (float*)d_out;

    const int N = in_sizes[0] / 128;
    const int E = in_sizes[1] / 2;
    const int nb   = (N + 511) >> 9;           // buckets (196)
    const int nbin = (E + 8191) / 8192;        // bin blocks (196)

    float* ws   = (float*)d_ws;
    float* asrc = ws;                                   // N*8 f
    float* adst = asrc + (size_t)N * 8;                 // N*8 f
    unsigned short* wt = (unsigned short*)(adst + (size_t)N * 8);     // 272*128 bf16
    unsigned short* xh_bf = wt + 272 * 128;             // N*128 bf16
    int* cntn   = (int*)(xh_bf + (size_t)N * 128);      // N
    int* rowptr = cntn + N;                             // N
    int* esrc   = rowptr + N;                           // E+8 (padded)
    int* fill   = esrc + E + 8;                         // 256
    unsigned* binned = (unsigned*)(fill + 256);         // nb*BCAP u32

    // zero esrc pad + fill in one shot (contiguous)
    hipMemsetAsync(esrc + E, 0, (8 + 256) * sizeof(int), stream);

    k0_wt<<<136, 256, 0, stream>>>(lin_w, skip_w, att_src, att_dst, wt);

    k1f<<<nbin + (N + 63) / 64, 512, 0, stream>>>(
        x, wt, gat_bias, skip_b, ei, xh_bf, asrc, adst, out,
        fill, binned, N, E, nbin);

    f3<<<nb, 256, 0, stream>>>(binned, fill, rowptr, cntn, esrc, N, nb);

    k3_agg<<<(N + 3) / 4, 256, 0, stream>>>(rowptr, cntn, esrc, asrc, adst,
                                            (const unsigned int*)xh_bf, out, N);
}

// Round 12
// 193.860 us; speedup vs baseline: 1.2950x; 1.0822x over previous
//
#include <hip/hip_runtime.h>
#include <math.h>

#define NEG 0.2f
#define BCAP 10240            // per-bucket slab capacity (mean 8163, +23 sigma)

typedef __attribute__((ext_vector_type(8))) short bf16x8;
typedef __attribute__((ext_vector_type(4))) float f32x4;

__device__ __forceinline__ unsigned short f2bf(float f) {
    unsigned u = __float_as_uint(f);
    u += 0x7fffu + ((u >> 16) & 1u);
    return (unsigned short)(u >> 16);
}
__device__ __forceinline__ unsigned pkbf(float a, float b) {
    return (unsigned)f2bf(a) | ((unsigned)f2bf(b) << 16);
}
__device__ __forceinline__ float blo(unsigned v) { return __uint_as_float(v << 16); }
__device__ __forceinline__ float bhi(unsigned v) { return __uint_as_float(v & 0xffff0000u); }
__device__ __forceinline__ float lrexp(float v) {
    v = v > 0.f ? v : NEG * v;
    return __expf(v);
}

// ---------------------------------------------------------------------------
// K0: build wt [272][128] bf16 transposed weights (lin | skip | w_as | w_ad)
// ---------------------------------------------------------------------------
__global__ __launch_bounds__(256) void k0_wt(
    const float* __restrict__ lin_w, const float* __restrict__ skip_w,
    const float* __restrict__ att_src, const float* __restrict__ att_dst,
    unsigned short* __restrict__ wt)
{
    int idx = blockIdx.x * 256 + threadIdx.x;   // 0..34815
    int c = idx >> 7, k = idx & 127;
    float v;
    if (c < 128) {
        v = lin_w[k * 128 + c];
    } else if (c < 256) {
        v = skip_w[k * 128 + (c - 128)];
    } else {
        int hh = c & 7;
        const float* att = (c & 8) ? att_dst : att_src;
        const float* wrow = lin_w + k * 128 + hh * 16;
        float s = 0.f;
#pragma unroll
        for (int j = 0; j < 16; ++j) s += wrow[j] * att[hh * 16 + j];
        v = s;
    }
    wt[c * 128 + k] = f2bf(v);
}

// ---------------------------------------------------------------------------
// K1F R12: [blocks 0..nbin) = edge binning (fixed-CAP slabs, u32 packed)
//          [blocks nbin..)  = persistent MFMA GEMM, transposed-D epilogue.
// mfma(bF, aF): lane owns x-row (lane&15), regs = 4 consecutive channels
// -> all epilogue stores vectorized (8B/16B), zero cross-lane ops.
// ---------------------------------------------------------------------------
__global__ __launch_bounds__(512) void k1f(
    const float* __restrict__ x, const unsigned short* __restrict__ wt,
    const float* __restrict__ gat_bias, const float* __restrict__ skip_b,
    const int* __restrict__ ei,
    unsigned short* __restrict__ xh_bf, float* __restrict__ a_src,
    float* __restrict__ a_dst, float* __restrict__ out,
    int* __restrict__ fill, unsigned* __restrict__ binned,
    int nrows, int E, int nbin, int ntiles, int G)
{
    __shared__ int s1[256];
    __shared__ int s2[256];
    const int t = threadIdx.x;
    const int bid = blockIdx.x;

    if (bid < nbin) {                 // ---- binning role ----
        if (t < 256) s1[t] = 0;
        __syncthreads();
        int eb = bid * 8192;
        int srcv[16], dstv[16], rkv[16];
#pragma unroll
        for (int u = 0; u < 16; ++u) {
            int e = eb + u * 512 + t;
            srcv[u] = 0; dstv[u] = -1; rkv[u] = 0;
            if (e < E) {
                srcv[u] = ei[e];
                dstv[u] = ei[E + e];
                rkv[u] = atomicAdd(&s1[dstv[u] >> 9], 1);
            }
        }
        __syncthreads();
        if (t < 256) {
            int hc = s1[t];
            s2[t] = t * BCAP + (hc ? atomicAdd(&fill[t], hc) : 0);
        }
        __syncthreads();
#pragma unroll
        for (int u = 0; u < 16; ++u) {
            if (dstv[u] >= 0) {
                int b = dstv[u] >> 9;
                binned[s2[b] + rkv[u]] =
                    ((unsigned)(dstv[u] & 511) << 17) | (unsigned)srcv[u];
            }
        }
        return;
    }

    // ---- persistent GEMM role ----
    const int w = t >> 6, l = t & 63, r = l & 15, half = l >> 4;
    const int cb = w >> 2;

    for (int tile = (bid - nbin); tile < ntiles; tile += G) {
        const int row0 = tile * 64 + (w & 3) * 16;
        const int row = row0 + r;                 // this lane's output row
        const bool rowok = row < nrows;
        const float* xrow = x + (size_t)row * 128;

        bf16x8 aF[4];
#pragma unroll
        for (int ks = 0; ks < 4; ++ks) {
            float4 v0 = make_float4(0.f, 0.f, 0.f, 0.f), v1 = v0;
            if (rowok) {
                const float* gp = xrow + ks * 32 + half * 8;
                v0 = *(const float4*)gp;
                v1 = *(const float4*)(gp + 4);
            }
            bf16x8 a;
            a[0] = f2bf(v0.x); a[1] = f2bf(v0.y); a[2] = f2bf(v0.z); a[3] = f2bf(v0.w);
            a[4] = f2bf(v1.x); a[5] = f2bf(v1.y); a[6] = f2bf(v1.z); a[7] = f2bf(v1.w);
            aF[ks] = a;
        }

        f32x4 acc[8];
#pragma unroll
        for (int cf = 0; cf < 8; ++cf) acc[cf] = (f32x4){0.f, 0.f, 0.f, 0.f};
        f32x4 accA = (f32x4){0.f, 0.f, 0.f, 0.f};

#pragma unroll
        for (int ks = 0; ks < 4; ++ks) {
#pragma unroll
            for (int cf = 0; cf < 8; ++cf) {
                const int c = cb * 128 + cf * 16 + r;
                bf16x8 bF = *(const bf16x8*)(wt + c * 128 + ks * 32 + half * 8);
                // swapped operands: D^T — lane&15 = x-row, reg = channel
                acc[cf] = __builtin_amdgcn_mfma_f32_16x16x32_bf16(bF, aF[ks], acc[cf], 0, 0, 0);
            }
            if (cb == 0) {
                bf16x8 bA = *(const bf16x8*)(wt + (256 + r) * 128 + ks * 32 + half * 8);
                accA = __builtin_amdgcn_mfma_f32_16x16x32_bf16(bA, aF[ks], accA, 0, 0, 0);
            }
        }

        if (rowok) {
            if (cb == 0) {    // lin half: xh (8B packed) + a_src/a_dst (16B)
#pragma unroll
                for (int cf = 0; cf < 8; ++cf) {
                    uint2 pk;
                    pk.x = pkbf(acc[cf][0], acc[cf][1]);
                    pk.y = pkbf(acc[cf][2], acc[cf][3]);
                    *(uint2*)(xh_bf + (size_t)row * 128 + cf * 16 + half * 4) = pk;
                }
                float* adst_base = (half < 2) ? a_src : a_dst;
                *(float4*)(adst_base + (size_t)row * 8 + (half & 1) * 4) =
                    make_float4(accA[0], accA[1], accA[2], accA[3]);
            } else {          // skip half: out = acc + biases (16B)
#pragma unroll
                for (int cf = 0; cf < 8; ++cf) {
                    const int c0 = cf * 16 + half * 4;
                    float4 g = *(const float4*)(gat_bias + c0);
                    float4 sbv = *(const float4*)(skip_b + c0);
                    *(float4*)(out + (size_t)row * 128 + c0) =
                        make_float4(acc[cf][0] + g.x + sbv.x, acc[cf][1] + g.y + sbv.y,
                                    acc[cf][2] + g.z + sbv.z, acc[cf][3] + g.w + sbv.w);
                }
            }
        }
    }
}

// ---------------------------------------------------------------------------
// F3: one block per bucket (512 nodes). Single pass: slab -> LDS, node hist,
// local scan -> rowptr/cntn, scatter esrc from LDS.
// ---------------------------------------------------------------------------
__global__ __launch_bounds__(256) void f3(
    const unsigned* __restrict__ binned, const int* __restrict__ fill,
    int* __restrict__ rowptr, int* __restrict__ cntn,
    int* __restrict__ esrc, int N, int nb)
{
    __shared__ unsigned le[BCAP];    // 40 KB
    __shared__ int bs[256];
    __shared__ int h[512];
    __shared__ int sc[256];
    const int t = threadIdx.x;
    const int b = blockIdx.x;

    int c = (t < nb) ? fill[t] : 0;
    bs[t] = c;
    __syncthreads();
    for (int off = 1; off < 256; off <<= 1) {
        int a = (t >= off) ? bs[t - off] : 0;
        __syncthreads();
        bs[t] += a;
        __syncthreads();
    }
    const int cnt = fill[b];
    const int baseE = bs[b] - cnt;

    h[t] = 0; h[t + 256] = 0;
    __syncthreads();
    for (int e = t; e < cnt; e += 256) {
        unsigned p = binned[b * BCAP + e];
        le[e] = p;
        atomicAdd(&h[p >> 17], 1);
    }
    __syncthreads();
    int i0 = 2 * t, i1 = i0 + 1;
    int c0 = h[i0], c1 = h[i1], pv = c0 + c1;
    sc[t] = pv;
    __syncthreads();
    for (int off = 1; off < 256; off <<= 1) {
        int a = (t >= off) ? sc[t - off] : 0;
        __syncthreads();
        sc[t] += a;
        __syncthreads();
    }
    int ex = sc[t] - pv;
    int n0 = b * 512 + i0;
    if (n0 < N)     { rowptr[n0]     = baseE + ex;      cntn[n0]     = c0; }
    if (n0 + 1 < N) { rowptr[n0 + 1] = baseE + ex + c0; cntn[n0 + 1] = c1; }
    h[i0] = baseE + ex;
    h[i1] = baseE + ex + c0;
    __syncthreads();
    for (int e = t; e < cnt; e += 256) {
        unsigned p = le[e];
        int slot = atomicAdd(&h[p >> 17], 1);
        esrc[slot] = (int)(p & 0x1FFFFu);
    }
}

// ---------------------------------------------------------------------------
// K3: fused denom + aggregation + skip + ELU (unchanged — at gather roofline)
// ---------------------------------------------------------------------------
__global__ __launch_bounds__(256) void k3_agg(
    const int* __restrict__ rowptr, const int* __restrict__ cntn,
    const int* __restrict__ esrc,
    const float* __restrict__ a_src, const float* __restrict__ a_dst,
    const unsigned int* __restrict__ xh32, float* __restrict__ out, int n)
{
    int i = blockIdx.x * 4 + (threadIdx.x >> 6);
    if (i >= n) return;
    const int lane = threadIdx.x & 63;
    const int h = lane >> 3, u = lane & 7;

    float adi = a_dst[(unsigned)i * 8 + h];
    float p0 = lrexp(a_src[(unsigned)i * 8 + h] + adi);
    unsigned uu = xh32[(unsigned)i * 64 + lane];
    float accx = p0 * blo(uu), accy = p0 * bhi(uu), den = p0;

    const int kbeg = rowptr[i], kend = kbeg + cntn[i];
    for (int k = kbeg; k < kend; k += 8) {
        int ke = k + u;
        int jm = esrc[ke];
        float pmv = lrexp(a_src[(unsigned)jm * 8 + h] + adi);
        float pm = (ke < kend) ? pmv : 0.f;

        int j0 = esrc[k],     j1 = esrc[k + 1], j2 = esrc[k + 2], j3 = esrc[k + 3];
        int j4 = esrc[k + 4], j5 = esrc[k + 5], j6 = esrc[k + 6], j7 = esrc[k + 7];
        unsigned g0 = xh32[(unsigned)j0 * 64 + lane];
        unsigned g1 = xh32[(unsigned)j1 * 64 + lane];
        unsigned g2 = xh32[(unsigned)j2 * 64 + lane];
        unsigned g3 = xh32[(unsigned)j3 * 64 + lane];
        unsigned g4 = xh32[(unsigned)j4 * 64 + lane];
        unsigned g5 = xh32[(unsigned)j5 * 64 + lane];
        unsigned g6 = xh32[(unsigned)j6 * 64 + lane];
        unsigned g7 = xh32[(unsigned)j7 * 64 + lane];

        int sb = lane & 56;
        float p;
        p = __shfl(pm, sb | 0, 64); accx += p * blo(g0); accy += p * bhi(g0); den += p;
        p = __shfl(pm, sb | 1, 64); accx += p * blo(g1); accy += p * bhi(g1); den += p;
        p = __shfl(pm, sb | 2, 64); accx += p * blo(g2); accy += p * bhi(g2); den += p;
        p = __shfl(pm, sb | 3, 64); accx += p * blo(g3); accy += p * bhi(g3); den += p;
        p = __shfl(pm, sb | 4, 64); accx += p * blo(g4); accy += p * bhi(g4); den += p;
        p = __shfl(pm, sb | 5, 64); accx += p * blo(g5); accy += p * bhi(g5); den += p;
        p = __shfl(pm, sb | 6, 64); accx += p * blo(g6); accy += p * bhi(g6); den += p;
        p = __shfl(pm, sb | 7, 64); accx += p * blo(g7); accy += p * bhi(g7); den += p;
    }

    float inv = 1.f / (den + 1e-16f);
    unsigned o = (unsigned)i * 128 + lane * 2;
    float o0 = out[o]     + accx * inv;
    float o1 = out[o + 1] + accy * inv;
    o0 = o0 > 0.f ? o0 : __expf(o0) - 1.f;
    o1 = o1 > 0.f ? o1 : __expf(o1) - 1.f;
    out[o]     = o0;
    out[o + 1] = o1;
}

extern "C" void kernel_launch(void* const* d_in, const int* in_sizes, int n_in,
                              void* d_out, int out_size, void* d_ws, size_t ws_size,
                              hipStream_t stream)
{
    const float* x        = (const float*)d_in[0];
    const int*   ei       = (const int*)d_in[1];
    const float* lin_w    = (const float*)d_in[2];
    const float* att_src  = (const float*)d_in[3];
    const float* att_dst  = (const float*)d_in[4];
    const float* gat_bias = (const float*)d_in[5];
    const float* skip_w   = (const float*)d_in[6];
    const float* skip_b   = (const float*)d_in[7];
    float* out = (float*)d_out;

    const int N = in_sizes[0] / 128;
    const int E = in_sizes[1] / 2;
    const int nb   = (N + 511) >> 9;           // buckets (196)
    const int nbin = (E + 8191) / 8192;        // bin blocks (196)
    const int ntiles = (N + 63) / 64;          // 64-row GEMM tiles
    const int G = (ntiles + 1) / 2;            // persistent GEMM blocks (2 tiles each)

    float* ws   = (float*)d_ws;
    float* asrc = ws;                                   // N*8 f
    float* adst = asrc + (size_t)N * 8;                 // N*8 f
    unsigned short* wt = (unsigned short*)(adst + (size_t)N * 8);     // 272*128 bf16
    unsigned short* xh_bf = wt + 272 * 128;             // N*128 bf16
    int* cntn   = (int*)(xh_bf + (size_t)N * 128);      // N
    int* rowptr = cntn + N;                             // N
    int* esrc   = rowptr + N;                           // E+8 (padded)
    int* fill   = esrc + E + 8;                         // 256
    unsigned* binned = (unsigned*)(fill + 256);         // nb*BCAP u32

    hipMemsetAsync(esrc + E, 0, (8 + 256) * sizeof(int), stream);

    k0_wt<<<136, 256, 0, stream>>>(lin_w, skip_w, att_src, att_dst, wt);

    k1f<<<nbin + G, 512, 0, stream>>>(
        x, wt, gat_bias, skip_b, ei, xh_bf, asrc, adst, out,
        fill, binned, N, E, nbin, ntiles, G);

    f3<<<nb, 256, 0, stream>>>(binned, fill, rowptr, cntn, esrc, N, nb);

    k3_agg<<<(N + 3) / 4, 256, 0, stream>>>(rowptr, cntn, esrc, asrc, adst,
                                            (const unsigned int*)xh_bf, out, N);
}

// Round 13
// 186.468 us; speedup vs baseline: 1.3463x; 1.0396x over previous
//
#include <hip/hip_runtime.h>
#include <math.h>

#define NEG 0.2f
#define BCAP 10240            // per-bucket slab capacity (mean 8163, +23 sigma)

typedef __attribute__((ext_vector_type(8))) short bf16x8;
typedef __attribute__((ext_vector_type(4))) float f32x4;

__device__ __forceinline__ unsigned short f2bf(float f) {
    unsigned u = __float_as_uint(f);
    u += 0x7fffu + ((u >> 16) & 1u);
    return (unsigned short)(u >> 16);
}
__device__ __forceinline__ unsigned pkbf(float a, float b) {
    return (unsigned)f2bf(a) | ((unsigned)f2bf(b) << 16);
}
__device__ __forceinline__ float blo(unsigned v) { return __uint_as_float(v << 16); }
__device__ __forceinline__ float bhi(unsigned v) { return __uint_as_float(v & 0xffff0000u); }
__device__ __forceinline__ float lrexp(float v) {
    v = v > 0.f ? v : NEG * v;
    return __expf(v);
}

// ---------------------------------------------------------------------------
// K0: build wt [272][128] bf16 transposed weights (lin | skip | w_as | w_ad)
// + zero the small scratch (esrc pad + fill) so no separate memset dispatch.
// ---------------------------------------------------------------------------
__global__ __launch_bounds__(256) void k0_wt(
    const float* __restrict__ lin_w, const float* __restrict__ skip_w,
    const float* __restrict__ att_src, const float* __restrict__ att_dst,
    unsigned short* __restrict__ wt, int* __restrict__ zbase)
{
    int idx = blockIdx.x * 256 + threadIdx.x;   // 0..34815
    if (blockIdx.x == 0) {
        for (int z = threadIdx.x; z < 264; z += 256) zbase[z] = 0;
    }
    int c = idx >> 7, k = idx & 127;
    float v;
    if (c < 128) {
        v = lin_w[k * 128 + c];
    } else if (c < 256) {
        v = skip_w[k * 128 + (c - 128)];
    } else {
        int hh = c & 7;
        const float* att = (c & 8) ? att_dst : att_src;
        const float* wrow = lin_w + k * 128 + hh * 16;
        float s = 0.f;
#pragma unroll
        for (int j = 0; j < 16; ++j) s += wrow[j] * att[hh * 16 + j];
        v = s;
    }
    wt[c * 128 + k] = f2bf(v);
}

// ---------------------------------------------------------------------------
// K1F: [blocks 0..nbin) = edge binning (fixed-CAP slabs, u32 packed)
//      [blocks nbin..)  = persistent MFMA GEMM, transposed-D epilogue.
// ---------------------------------------------------------------------------
__global__ __launch_bounds__(512) void k1f(
    const float* __restrict__ x, const unsigned short* __restrict__ wt,
    const float* __restrict__ gat_bias, const float* __restrict__ skip_b,
    const int* __restrict__ ei,
    unsigned short* __restrict__ xh_bf, float* __restrict__ a_src,
    float* __restrict__ a_dst, float* __restrict__ out,
    int* __restrict__ fill, unsigned* __restrict__ binned,
    int nrows, int E, int nbin, int ntiles, int G)
{
    __shared__ int s1[256];
    __shared__ int s2[256];
    const int t = threadIdx.x;
    const int bid = blockIdx.x;

    if (bid < nbin) {                 // ---- binning role ----
        if (t < 256) s1[t] = 0;
        __syncthreads();
        int eb = bid * 8192;
        int srcv[16], dstv[16], rkv[16];
#pragma unroll
        for (int u = 0; u < 16; ++u) {
            int e = eb + u * 512 + t;
            srcv[u] = 0; dstv[u] = -1; rkv[u] = 0;
            if (e < E) {
                srcv[u] = ei[e];
                dstv[u] = ei[E + e];
                rkv[u] = atomicAdd(&s1[dstv[u] >> 9], 1);
            }
        }
        __syncthreads();
        if (t < 256) {
            int hc = s1[t];
            s2[t] = t * BCAP + (hc ? atomicAdd(&fill[t], hc) : 0);
        }
        __syncthreads();
#pragma unroll
        for (int u = 0; u < 16; ++u) {
            if (dstv[u] >= 0) {
                int b = dstv[u] >> 9;
                binned[s2[b] + rkv[u]] =
                    ((unsigned)(dstv[u] & 511) << 17) | (unsigned)srcv[u];
            }
        }
        return;
    }

    // ---- persistent GEMM role ----
    const int w = t >> 6, l = t & 63, r = l & 15, half = l >> 4;
    const int cb = w >> 2;

    for (int tile = (bid - nbin); tile < ntiles; tile += G) {
        const int row0 = tile * 64 + (w & 3) * 16;
        const int row = row0 + r;
        const bool rowok = row < nrows;
        const float* xrow = x + (size_t)row * 128;

        bf16x8 aF[4];
#pragma unroll
        for (int ks = 0; ks < 4; ++ks) {
            float4 v0 = make_float4(0.f, 0.f, 0.f, 0.f), v1 = v0;
            if (rowok) {
                const float* gp = xrow + ks * 32 + half * 8;
                v0 = *(const float4*)gp;
                v1 = *(const float4*)(gp + 4);
            }
            bf16x8 a;
            a[0] = f2bf(v0.x); a[1] = f2bf(v0.y); a[2] = f2bf(v0.z); a[3] = f2bf(v0.w);
            a[4] = f2bf(v1.x); a[5] = f2bf(v1.y); a[6] = f2bf(v1.z); a[7] = f2bf(v1.w);
            aF[ks] = a;
        }

        f32x4 acc[8];
#pragma unroll
        for (int cf = 0; cf < 8; ++cf) acc[cf] = (f32x4){0.f, 0.f, 0.f, 0.f};
        f32x4 accA = (f32x4){0.f, 0.f, 0.f, 0.f};

#pragma unroll
        for (int ks = 0; ks < 4; ++ks) {
#pragma unroll
            for (int cf = 0; cf < 8; ++cf) {
                const int c = cb * 128 + cf * 16 + r;
                bf16x8 bF = *(const bf16x8*)(wt + c * 128 + ks * 32 + half * 8);
                acc[cf] = __builtin_amdgcn_mfma_f32_16x16x32_bf16(bF, aF[ks], acc[cf], 0, 0, 0);
            }
            if (cb == 0) {
                bf16x8 bA = *(const bf16x8*)(wt + (256 + r) * 128 + ks * 32 + half * 8);
                accA = __builtin_amdgcn_mfma_f32_16x16x32_bf16(bA, aF[ks], accA, 0, 0, 0);
            }
        }

        if (rowok) {
            if (cb == 0) {
#pragma unroll
                for (int cf = 0; cf < 8; ++cf) {
                    uint2 pk;
                    pk.x = pkbf(acc[cf][0], acc[cf][1]);
                    pk.y = pkbf(acc[cf][2], acc[cf][3]);
                    *(uint2*)(xh_bf + (size_t)row * 128 + cf * 16 + half * 4) = pk;
                }
                float* adst_base = (half < 2) ? a_src : a_dst;
                *(float4*)(adst_base + (size_t)row * 8 + (half & 1) * 4) =
                    make_float4(accA[0], accA[1], accA[2], accA[3]);
            } else {
#pragma unroll
                for (int cf = 0; cf < 8; ++cf) {
                    const int c0 = cf * 16 + half * 4;
                    float4 g = *(const float4*)(gat_bias + c0);
                    float4 sbv = *(const float4*)(skip_b + c0);
                    *(float4*)(out + (size_t)row * 128 + c0) =
                        make_float4(acc[cf][0] + g.x + sbv.x, acc[cf][1] + g.y + sbv.y,
                                    acc[cf][2] + g.z + sbv.z, acc[cf][3] + g.w + sbv.w);
                }
            }
        }
    }
}

// ---------------------------------------------------------------------------
// F3: one block per bucket (512 nodes). Single pass: slab -> LDS, node hist,
// local scan -> rowptr/cntn, scatter esrc from LDS.
// ---------------------------------------------------------------------------
__global__ __launch_bounds__(256) void f3(
    const unsigned* __restrict__ binned, const int* __restrict__ fill,
    int* __restrict__ rowptr, int* __restrict__ cntn,
    int* __restrict__ esrc, int N, int nb)
{
    __shared__ unsigned le[BCAP];    // 40 KB
    __shared__ int bs[256];
    __shared__ int h[512];
    __shared__ int sc[256];
    const int t = threadIdx.x;
    const int b = blockIdx.x;

    int c = (t < nb) ? fill[t] : 0;
    bs[t] = c;
    __syncthreads();
    for (int off = 1; off < 256; off <<= 1) {
        int a = (t >= off) ? bs[t - off] : 0;
        __syncthreads();
        bs[t] += a;
        __syncthreads();
    }
    const int cnt = fill[b];
    const int baseE = bs[b] - cnt;

    h[t] = 0; h[t + 256] = 0;
    __syncthreads();
    for (int e = t; e < cnt; e += 256) {
        unsigned p = binned[b * BCAP + e];
        le[e] = p;
        atomicAdd(&h[p >> 17], 1);
    }
    __syncthreads();
    int i0 = 2 * t, i1 = i0 + 1;
    int c0 = h[i0], c1 = h[i1], pv = c0 + c1;
    sc[t] = pv;
    __syncthreads();
    for (int off = 1; off < 256; off <<= 1) {
        int a = (t >= off) ? sc[t - off] : 0;
        __syncthreads();
        sc[t] += a;
        __syncthreads();
    }
    int ex = sc[t] - pv;
    int n0 = b * 512 + i0;
    if (n0 < N)     { rowptr[n0]     = baseE + ex;      cntn[n0]     = c0; }
    if (n0 + 1 < N) { rowptr[n0 + 1] = baseE + ex + c0; cntn[n0 + 1] = c1; }
    h[i0] = baseE + ex;
    h[i1] = baseE + ex + c0;
    __syncthreads();
    for (int e = t; e < cnt; e += 256) {
        unsigned p = le[e];
        int slot = atomicAdd(&h[p >> 17], 1);
        esrc[slot] = (int)(p & 0x1FFFFu);
    }
}

// ---------------------------------------------------------------------------
// K3 R13: tail gathers clamped to the last real edge (re-fetch = L1 hit)
// instead of reading the next row's random lines. Math identical (pm=0).
// ---------------------------------------------------------------------------
__global__ __launch_bounds__(256) void k3_agg(
    const int* __restrict__ rowptr, const int* __restrict__ cntn,
    const int* __restrict__ esrc,
    const float* __restrict__ a_src, const float* __restrict__ a_dst,
    const unsigned int* __restrict__ xh32, float* __restrict__ out, int n)
{
    int i = blockIdx.x * 4 + (threadIdx.x >> 6);
    if (i >= n) return;
    const int lane = threadIdx.x & 63;
    const int h = lane >> 3, u = lane & 7;

    float adi = a_dst[(unsigned)i * 8 + h];
    float p0 = lrexp(a_src[(unsigned)i * 8 + h] + adi);
    unsigned uu = xh32[(unsigned)i * 64 + lane];
    float accx = p0 * blo(uu), accy = p0 * bhi(uu), den = p0;

    const int kbeg = rowptr[i], kend = kbeg + cntn[i];
    const int kl = kend - 1;
    for (int k = kbeg; k < kend; k += 8) {
        int ke = k + u;
        int jm = esrc[min(ke, kl)];
        float pmv = lrexp(a_src[(unsigned)jm * 8 + h] + adi);
        float pm = (ke < kend) ? pmv : 0.f;

        int j0 = esrc[min(k + 0, kl)], j1 = esrc[min(k + 1, kl)];
        int j2 = esrc[min(k + 2, kl)], j3 = esrc[min(k + 3, kl)];
        int j4 = esrc[min(k + 4, kl)], j5 = esrc[min(k + 5, kl)];
        int j6 = esrc[min(k + 6, kl)], j7 = esrc[min(k + 7, kl)];
        unsigned g0 = xh32[(unsigned)j0 * 64 + lane];
        unsigned g1 = xh32[(unsigned)j1 * 64 + lane];
        unsigned g2 = xh32[(unsigned)j2 * 64 + lane];
        unsigned g3 = xh32[(unsigned)j3 * 64 + lane];
        unsigned g4 = xh32[(unsigned)j4 * 64 + lane];
        unsigned g5 = xh32[(unsigned)j5 * 64 + lane];
        unsigned g6 = xh32[(unsigned)j6 * 64 + lane];
        unsigned g7 = xh32[(unsigned)j7 * 64 + lane];

        int sb = lane & 56;
        float p;
        p = __shfl(pm, sb | 0, 64); accx += p * blo(g0); accy += p * bhi(g0); den += p;
        p = __shfl(pm, sb | 1, 64); accx += p * blo(g1); accy += p * bhi(g1); den += p;
        p = __shfl(pm, sb | 2, 64); accx += p * blo(g2); accy += p * bhi(g2); den += p;
        p = __shfl(pm, sb | 3, 64); accx += p * blo(g3); accy += p * bhi(g3); den += p;
        p = __shfl(pm, sb | 4, 64); accx += p * blo(g4); accy += p * bhi(g4); den += p;
        p = __shfl(pm, sb | 5, 64); accx += p * blo(g5); accy += p * bhi(g5); den += p;
        p = __shfl(pm, sb | 6, 64); accx += p * blo(g6); accy += p * bhi(g6); den += p;
        p = __shfl(pm, sb | 7, 64); accx += p * blo(g7); accy += p * bhi(g7); den += p;
    }

    float inv = 1.f / (den + 1e-16f);
    unsigned o = (unsigned)i * 128 + lane * 2;
    float o0 = out[o]     + accx * inv;
    float o1 = out[o + 1] + accy * inv;
    o0 = o0 > 0.f ? o0 : __expf(o0) - 1.f;
    o1 = o1 > 0.f ? o1 : __expf(o1) - 1.f;
    out[o]     = o0;
    out[o + 1] = o1;
}

extern "C" void kernel_launch(void* const* d_in, const int* in_sizes, int n_in,
                              void* d_out, int out_size, void* d_ws, size_t ws_size,
                              hipStream_t stream)
{
    const float* x        = (const float*)d_in[0];
    const int*   ei       = (const int*)d_in[1];
    const float* lin_w    = (const float*)d_in[2];
    const float* att_src  = (const float*)d_in[3];
    const float* att_dst  = (const float*)d_in[4];
    const float* gat_bias = (const float*)d_in[5];
    const float* skip_w   = (const float*)d_in[6];
    const float* skip_b   = (const float*)d_in[7];
    float* out = (float*)d_out;

    const int N = in_sizes[0] / 128;
    const int E = in_sizes[1] / 2;
    const int nb   = (N + 511) >> 9;           // buckets (196)
    const int nbin = (E + 8191) / 8192;        // bin blocks (196)
    const int ntiles = (N + 63) / 64;
    const int G = (ntiles + 1) / 2;            // persistent GEMM blocks

    float* ws   = (float*)d_ws;
    float* asrc = ws;                                   // N*8 f
    float* adst = asrc + (size_t)N * 8;                 // N*8 f
    unsigned short* wt = (unsigned short*)(adst + (size_t)N * 8);     // 272*128 bf16
    unsigned short* xh_bf = wt + 272 * 128;             // N*128 bf16
    int* cntn   = (int*)(xh_bf + (size_t)N * 128);      // N
    int* rowptr = cntn + N;                             // N
    int* esrc   = rowptr + N;                           // E+8 (padded)
    int* fill   = esrc + E + 8;                         // 256
    unsigned* binned = (unsigned*)(fill + 256);         // nb*BCAP u32

    k0_wt<<<136, 256, 0, stream>>>(lin_w, skip_w, att_src, att_dst, wt, esrc + E);

    k1f<<<nbin + G, 512, 0, stream>>>(
        x, wt, gat_bias, skip_b, ei, xh_bf, asrc, adst, out,
        fill, binned, N, E, nbin, ntiles, G);

    f3<<<nb, 256, 0, stream>>>(binned, fill, rowptr, cntn, esrc, N, nb);

    k3_agg<<<(N + 3) / 4, 256, 0, stream>>>(rowptr, cntn, esrc, asrc, adst,
                                            (const unsigned int*)xh_bf, out, N);
}

// Round 14
// 169.915 us; speedup vs baseline: 1.4775x; 1.0974x over previous
//
#include <hip/hip_runtime.h>
#include <math.h>

#define NEG 0.2f
#define BCAP 10240            // per-bucket slab capacity (mean 8163, +23 sigma)

typedef __attribute__((ext_vector_type(8))) short bf16x8;
typedef __attribute__((ext_vector_type(4))) float f32x4;

__device__ __forceinline__ unsigned short f2bf(float f) {
    unsigned u = __float_as_uint(f);
    u += 0x7fffu + ((u >> 16) & 1u);
    return (unsigned short)(u >> 16);
}
__device__ __forceinline__ unsigned pkbf(float a, float b) {
    return (unsigned)f2bf(a) | ((unsigned)f2bf(b) << 16);
}
__device__ __forceinline__ float blo(unsigned v) { return __uint_as_float(v << 16); }
__device__ __forceinline__ float bhi(unsigned v) { return __uint_as_float(v & 0xffff0000u); }
__device__ __forceinline__ float lrexp(float v) {
    v = v > 0.f ? v : NEG * v;
    return __expf(v);
}

// ---------------------------------------------------------------------------
// K0: build wt [272][128] bf16 transposed weights (lin | skip | w_as | w_ad)
// + zero the small scratch (esrc pad + fill).
// ---------------------------------------------------------------------------
__global__ __launch_bounds__(256) void k0_wt(
    const float* __restrict__ lin_w, const float* __restrict__ skip_w,
    const float* __restrict__ att_src, const float* __restrict__ att_dst,
    unsigned short* __restrict__ wt, int* __restrict__ zbase)
{
    int idx = blockIdx.x * 256 + threadIdx.x;   // 0..34815
    if (blockIdx.x == 0) {
        for (int z = threadIdx.x; z < 264; z += 256) zbase[z] = 0;
    }
    int c = idx >> 7, k = idx & 127;
    float v;
    if (c < 128) {
        v = lin_w[k * 128 + c];
    } else if (c < 256) {
        v = skip_w[k * 128 + (c - 128)];
    } else {
        int hh = c & 7;
        const float* att = (c & 8) ? att_dst : att_src;
        const float* wrow = lin_w + k * 128 + hh * 16;
        float s = 0.f;
#pragma unroll
        for (int j = 0; j < 16; ++j) s += wrow[j] * att[hh * 16 + j];
        v = s;
    }
    wt[c * 128 + k] = f2bf(v);
}

// ---------------------------------------------------------------------------
// K1F R14: [blocks 0..nbin) = edge binning (fixed-CAP slabs, u32 packed)
//          [blocks nbin..)  = persistent MFMA GEMM, B-STATIONARY registers.
// B fragments are tile-invariant -> loaded ONCE per wave before the tile
// loop (32 bf16x8 + 4 bA / 8 bias float4). Per tile: 4 A-loads + MFMA + store.
// ---------------------------------------------------------------------------
__global__ __launch_bounds__(512, 2) void k1f(
    const float* __restrict__ x, const unsigned short* __restrict__ wt,
    const float* __restrict__ gat_bias, const float* __restrict__ skip_b,
    const int* __restrict__ ei,
    unsigned short* __restrict__ xh_bf, float* __restrict__ a_src,
    float* __restrict__ a_dst, float* __restrict__ out,
    int* __restrict__ fill, unsigned* __restrict__ binned,
    int nrows, int E, int nbin, int ntiles, int G)
{
    __shared__ int s1[256];
    __shared__ int s2[256];
    const int t = threadIdx.x;
    const int bid = blockIdx.x;

    if (bid < nbin) {                 // ---- binning role ----
        if (t < 256) s1[t] = 0;
        __syncthreads();
        int eb = bid * 8192;
        int srcv[16], dstv[16], rkv[16];
#pragma unroll
        for (int u = 0; u < 16; ++u) {
            int e = eb + u * 512 + t;
            srcv[u] = 0; dstv[u] = -1; rkv[u] = 0;
            if (e < E) {
                srcv[u] = ei[e];
                dstv[u] = ei[E + e];
                rkv[u] = atomicAdd(&s1[dstv[u] >> 9], 1);
            }
        }
        __syncthreads();
        if (t < 256) {
            int hc = s1[t];
            s2[t] = t * BCAP + (hc ? atomicAdd(&fill[t], hc) : 0);
        }
        __syncthreads();
#pragma unroll
        for (int u = 0; u < 16; ++u) {
            if (dstv[u] >= 0) {
                int b = dstv[u] >> 9;
                binned[s2[b] + rkv[u]] =
                    ((unsigned)(dstv[u] & 511) << 17) | (unsigned)srcv[u];
            }
        }
        return;
    }

    // ---- persistent GEMM role, B-stationary ----
    const int w = t >> 6, l = t & 63, r = l & 15, half = l >> 4;
    const int cb = w >> 2;

    // Load all tile-invariant B fragments ONCE.
    bf16x8 Bf[4][8];                 // [ks][cf]
#pragma unroll
    for (int ks = 0; ks < 4; ++ks)
#pragma unroll
        for (int cf = 0; cf < 8; ++cf) {
            const int c = cb * 128 + cf * 16 + r;
            Bf[ks][cf] = *(const bf16x8*)(wt + c * 128 + ks * 32 + half * 8);
        }
    bf16x8 bA[4];
    float4 gb[8];
    if (cb == 0) {
#pragma unroll
        for (int ks = 0; ks < 4; ++ks)
            bA[ks] = *(const bf16x8*)(wt + (256 + r) * 128 + ks * 32 + half * 8);
    } else {
#pragma unroll
        for (int cf = 0; cf < 8; ++cf) {
            const int c0 = cf * 16 + half * 4;
            float4 g = *(const float4*)(gat_bias + c0);
            float4 sb = *(const float4*)(skip_b + c0);
            gb[cf] = make_float4(g.x + sb.x, g.y + sb.y, g.z + sb.z, g.w + sb.w);
        }
    }

    for (int tile = (bid - nbin); tile < ntiles; tile += G) {
        const int row0 = tile * 64 + (w & 3) * 16;
        const int row = row0 + r;
        const bool rowok = row < nrows;
        const float* xrow = x + (size_t)row * 128;

        bf16x8 aF[4];
#pragma unroll
        for (int ks = 0; ks < 4; ++ks) {
            float4 v0 = make_float4(0.f, 0.f, 0.f, 0.f), v1 = v0;
            if (rowok) {
                const float* gp = xrow + ks * 32 + half * 8;
                v0 = *(const float4*)gp;
                v1 = *(const float4*)(gp + 4);
            }
            bf16x8 a;
            a[0] = f2bf(v0.x); a[1] = f2bf(v0.y); a[2] = f2bf(v0.z); a[3] = f2bf(v0.w);
            a[4] = f2bf(v1.x); a[5] = f2bf(v1.y); a[6] = f2bf(v1.z); a[7] = f2bf(v1.w);
            aF[ks] = a;
        }

        f32x4 acc[8];
#pragma unroll
        for (int cf = 0; cf < 8; ++cf) acc[cf] = (f32x4){0.f, 0.f, 0.f, 0.f};
        f32x4 accA = (f32x4){0.f, 0.f, 0.f, 0.f};

#pragma unroll
        for (int ks = 0; ks < 4; ++ks) {
#pragma unroll
            for (int cf = 0; cf < 8; ++cf)
                acc[cf] = __builtin_amdgcn_mfma_f32_16x16x32_bf16(Bf[ks][cf], aF[ks], acc[cf], 0, 0, 0);
            if (cb == 0)
                accA = __builtin_amdgcn_mfma_f32_16x16x32_bf16(bA[ks], aF[ks], accA, 0, 0, 0);
        }

        if (rowok) {
            if (cb == 0) {    // lin half: xh (8B packed) + a_src/a_dst (16B)
#pragma unroll
                for (int cf = 0; cf < 8; ++cf) {
                    uint2 pk;
                    pk.x = pkbf(acc[cf][0], acc[cf][1]);
                    pk.y = pkbf(acc[cf][2], acc[cf][3]);
                    *(uint2*)(xh_bf + (size_t)row * 128 + cf * 16 + half * 4) = pk;
                }
                float* adst_base = (half < 2) ? a_src : a_dst;
                *(float4*)(adst_base + (size_t)row * 8 + (half & 1) * 4) =
                    make_float4(accA[0], accA[1], accA[2], accA[3]);
            } else {          // skip half: out = acc + biases (16B)
#pragma unroll
                for (int cf = 0; cf < 8; ++cf) {
                    const int c0 = cf * 16 + half * 4;
                    *(float4*)(out + (size_t)row * 128 + c0) =
                        make_float4(acc[cf][0] + gb[cf].x, acc[cf][1] + gb[cf].y,
                                    acc[cf][2] + gb[cf].z, acc[cf][3] + gb[cf].w);
                }
            }
        }
    }
}

// ---------------------------------------------------------------------------
// F3: one block per bucket (512 nodes). Single pass: slab -> LDS, node hist,
// local scan -> rowptr/cntn, scatter esrc from LDS.
// ---------------------------------------------------------------------------
__global__ __launch_bounds__(256) void f3(
    const unsigned* __restrict__ binned, const int* __restrict__ fill,
    int* __restrict__ rowptr, int* __restrict__ cntn,
    int* __restrict__ esrc, int N, int nb)
{
    __shared__ unsigned le[BCAP];    // 40 KB
    __shared__ int bs[256];
    __shared__ int h[512];
    __shared__ int sc[256];
    const int t = threadIdx.x;
    const int b = blockIdx.x;

    int c = (t < nb) ? fill[t] : 0;
    bs[t] = c;
    __syncthreads();
    for (int off = 1; off < 256; off <<= 1) {
        int a = (t >= off) ? bs[t - off] : 0;
        __syncthreads();
        bs[t] += a;
        __syncthreads();
    }
    const int cnt = fill[b];
    const int baseE = bs[b] - cnt;

    h[t] = 0; h[t + 256] = 0;
    __syncthreads();
    for (int e = t; e < cnt; e += 256) {
        unsigned p = binned[b * BCAP + e];
        le[e] = p;
        atomicAdd(&h[p >> 17], 1);
    }
    __syncthreads();
    int i0 = 2 * t, i1 = i0 + 1;
    int c0 = h[i0], c1 = h[i1], pv = c0 + c1;
    sc[t] = pv;
    __syncthreads();
    for (int off = 1; off < 256; off <<= 1) {
        int a = (t >= off) ? sc[t - off] : 0;
        __syncthreads();
        sc[t] += a;
        __syncthreads();
    }
    int ex = sc[t] - pv;
    int n0 = b * 512 + i0;
    if (n0 < N)     { rowptr[n0]     = baseE + ex;      cntn[n0]     = c0; }
    if (n0 + 1 < N) { rowptr[n0 + 1] = baseE + ex + c0; cntn[n0 + 1] = c1; }
    h[i0] = baseE + ex;
    h[i1] = baseE + ex + c0;
    __syncthreads();
    for (int e = t; e < cnt; e += 256) {
        unsigned p = le[e];
        int slot = atomicAdd(&h[p >> 17], 1);
        esrc[slot] = (int)(p & 0x1FFFFu);
    }
}

// ---------------------------------------------------------------------------
// K3: tail-clamped gather aggregation (unchanged from R13 — at gather floor)
// ---------------------------------------------------------------------------
__global__ __launch_bounds__(256) void k3_agg(
    const int* __restrict__ rowptr, const int* __restrict__ cntn,
    const int* __restrict__ esrc,
    const float* __restrict__ a_src, const float* __restrict__ a_dst,
    const unsigned int* __restrict__ xh32, float* __restrict__ out, int n)
{
    int i = blockIdx.x * 4 + (threadIdx.x >> 6);
    if (i >= n) return;
    const int lane = threadIdx.x & 63;
    const int h = lane >> 3, u = lane & 7;

    float adi = a_dst[(unsigned)i * 8 + h];
    float p0 = lrexp(a_src[(unsigned)i * 8 + h] + adi);
    unsigned uu = xh32[(unsigned)i * 64 + lane];
    float accx = p0 * blo(uu), accy = p0 * bhi(uu), den = p0;

    const int kbeg = rowptr[i], kend = kbeg + cntn[i];
    const int kl = kend - 1;
    for (int k = kbeg; k < kend; k += 8) {
        int ke = k + u;
        int jm = esrc[min(ke, kl)];
        float pmv = lrexp(a_src[(unsigned)jm * 8 + h] + adi);
        float pm = (ke < kend) ? pmv : 0.f;

        int j0 = esrc[min(k + 0, kl)], j1 = esrc[min(k + 1, kl)];
        int j2 = esrc[min(k + 2, kl)], j3 = esrc[min(k + 3, kl)];
        int j4 = esrc[min(k + 4, kl)], j5 = esrc[min(k + 5, kl)];
        int j6 = esrc[min(k + 6, kl)], j7 = esrc[min(k + 7, kl)];
        unsigned g0 = xh32[(unsigned)j0 * 64 + lane];
        unsigned g1 = xh32[(unsigned)j1 * 64 + lane];
        unsigned g2 = xh32[(unsigned)j2 * 64 + lane];
        unsigned g3 = xh32[(unsigned)j3 * 64 + lane];
        unsigned g4 = xh32[(unsigned)j4 * 64 + lane];
        unsigned g5 = xh32[(unsigned)j5 * 64 + lane];
        unsigned g6 = xh32[(unsigned)j6 * 64 + lane];
        unsigned g7 = xh32[(unsigned)j7 * 64 + lane];

        int sb = lane & 56;
        float p;
        p = __shfl(pm, sb | 0, 64); accx += p * blo(g0); accy += p * bhi(g0); den += p;
        p = __shfl(pm, sb | 1, 64); accx += p * blo(g1); accy += p * bhi(g1); den += p;
        p = __shfl(pm, sb | 2, 64); accx += p * blo(g2); accy += p * bhi(g2); den += p;
        p = __shfl(pm, sb | 3, 64); accx += p * blo(g3); accy += p * bhi(g3); den += p;
        p = __shfl(pm, sb | 4, 64); accx += p * blo(g4); accy += p * bhi(g4); den += p;
        p = __shfl(pm, sb | 5, 64); accx += p * blo(g5); accy += p * bhi(g5); den += p;
        p = __shfl(pm, sb | 6, 64); accx += p * blo(g6); accy += p * bhi(g6); den += p;
        p = __shfl(pm, sb | 7, 64); accx += p * blo(g7); accy += p * bhi(g7); den += p;
    }

    float inv = 1.f / (den + 1e-16f);
    unsigned o = (unsigned)i * 128 + lane * 2;
    float o0 = out[o]     + accx * inv;
    float o1 = out[o + 1] + accy * inv;
    o0 = o0 > 0.f ? o0 : __expf(o0) - 1.f;
    o1 = o1 > 0.f ? o1 : __expf(o1) - 1.f;
    out[o]     = o0;
    out[o + 1] = o1;
}

extern "C" void kernel_launch(void* const* d_in, const int* in_sizes, int n_in,
                              void* d_out, int out_size, void* d_ws, size_t ws_size,
                              hipStream_t stream)
{
    const float* x        = (const float*)d_in[0];
    const int*   ei       = (const int*)d_in[1];
    const float* lin_w    = (const float*)d_in[2];
    const float* att_src  = (const float*)d_in[3];
    const float* att_dst  = (const float*)d_in[4];
    const float* gat_bias = (const float*)d_in[5];
    const float* skip_w   = (const float*)d_in[6];
    const float* skip_b   = (const float*)d_in[7];
    float* out = (float*)d_out;

    const int N = in_sizes[0] / 128;
    const int E = in_sizes[1] / 2;
    const int nb   = (N + 511) >> 9;           // buckets (196)
    const int nbin = (E + 8191) / 8192;        // bin blocks (196)
    const int ntiles = (N + 63) / 64;
    int G = 2 * 256 - nbin;                    // ~2 residency rounds at 1 blk/CU
    if (G < 64) G = 64;
    if (G > ntiles) G = ntiles;

    float* ws   = (float*)d_ws;
    float* asrc = ws;                                   // N*8 f
    float* adst = asrc + (size_t)N * 8;                 // N*8 f
    unsigned short* wt = (unsigned short*)(adst + (size_t)N * 8);     // 272*128 bf16
    unsigned short* xh_bf = wt + 272 * 128;             // N*128 bf16
    int* cntn   = (int*)(xh_bf + (size_t)N * 128);      // N
    int* rowptr = cntn + N;                             // N
    int* esrc   = rowptr + N;                           // E+8 (padded)
    int* fill   = esrc + E + 8;                         // 256
    unsigned* binned = (unsigned*)(fill + 256);         // nb*BCAP u32

    k0_wt<<<136, 256, 0, stream>>>(lin_w, skip_w, att_src, att_dst, wt, esrc + E);

    k1f<<<nbin + G, 512, 0, stream>>>(
        x, wt, gat_bias, skip_b, ei, xh_bf, asrc, adst, out,
        fill, binned, N, E, nbin, ntiles, G);

    f3<<<nb, 256, 0, stream>>>(binned, fill, rowptr, cntn, esrc, N, nb);

    k3_agg<<<(N + 3) / 4, 256, 0, stream>>>(rowptr, cntn, esrc, asrc, adst,
                                            (const unsigned int*)xh_bf, out, N);
}